// Round 4
// baseline (1563.084 us; speedup 1.0000x reference)
//
#include <hip/hip_runtime.h>
#include <math.h>

// Problem constants (match reference)
#define NROWS   8192
#define DDIM    1024
#define NSTEPS  50
#define EPL     16          // elements per lane: 1024 / 64
#define WPB     4           // waves per block -> 256 threads

// Adam hyperparams (double for host-side table computation)
#define LR_D   0.01
#define B1_D   0.9
#define B2_D   0.999
#define EPS_D  1e-8

struct StepTbl {
    float alpha[NSTEPS];   // LR*(1-B1)*sqrt((1-B2^t)/(1-B2))/(1-B1^t)
    float eps2[NSTEPS];    // EPS*sqrt((1-B2^t)/(1-B2))
};

__global__ __launch_bounds__(256, 4) void adam_rows_kernel(
    const float* __restrict__ s,       // [NROWS, DDIM]
    const float* __restrict__ tconf,   // [NROWS, 1]
    const float* __restrict__ W,       // [1, DDIM]
    const float* __restrict__ bias,    // [1]
    float* __restrict__ out,           // [NROWS, DDIM]
    const StepTbl tbl)
{
    const int lane = threadIdx.x & 63;
    const int wave = threadIdx.x >> 6;
    const int row  = blockIdx.x * WPB + wave;

    const float bb = bias[0];
    const float tc = tconf[row];

    const float B1f = 0.9f;
    const float B2f = 0.999f;
    const float GZS = 2.0f / (float)NROWS;
    const float INV_NL1  = 1.1920929e-7f;   // 2^-23 == 1/(NROWS*DDIM) exactly
    const float SIGN_MUL = 3.4e38f;         // lifts any nonzero |diff| above 2^-23
    const float NLOG2E   = -1.44269504f;
    const float YMAX     = 1e30f;

    // State: w (shared weights), diff = sp - s0, scaled Adam M/V,
    // y ~= rsqrt(V), r ~= 1/(sqrt(V)+eps2)
    float w[EPL], diff[EPL], M[EPL], V[EPL], y[EPL], r[EPL];

    const float4* W4 = reinterpret_cast<const float4*>(W);
    const float4* S4 = reinterpret_cast<const float4*>(s + (size_t)row * DDIM);

    // Load w; compute dot0 = s0 . w (s0 not kept in registers)
    float dot0 = 0.0f;
    #pragma unroll
    for (int c = 0; c < 4; ++c) {
        float4 wv = W4[c * 64 + lane];
        float4 sv = S4[c * 64 + lane];
        w[c*4+0] = wv.x; w[c*4+1] = wv.y; w[c*4+2] = wv.z; w[c*4+3] = wv.w;
        dot0 = fmaf(sv.x, wv.x, dot0);
        dot0 = fmaf(sv.y, wv.y, dot0);
        dot0 = fmaf(sv.z, wv.z, dot0);
        dot0 = fmaf(sv.w, wv.w, dot0);
    }
    #pragma unroll
    for (int off = 32; off >= 1; off >>= 1) dot0 += __shfl_xor(dot0, off, 64);
    const float zb = dot0 + bb;   // z = zb + (diff . w), and diff starts at 0

    float ddot = 0.0f;   // diff . w (per-lane partial, reduced at top of each step)

    // ---- Step 0 (t=1): diff == 0 -> sign term is exactly 0 ----
    {
        const float e  = __builtin_amdgcn_exp2f(zb * NLOG2E);
        const float p  = __builtin_amdgcn_rcpf(1.0f + e);
        const float gz = GZS * (p - tc) * (p * (1.0f - p));
        const float a0 = tbl.alpha[0];
        const float e0 = tbl.eps2[0];
        #pragma unroll
        for (int i = 0; i < EPL; ++i) {
            const float g = gz * w[i];
            M[i] = g;
            V[i] = g * g;
            const float den = fabsf(g) + e0;                    // sqrt(g^2) + eps
            r[i] = __builtin_amdgcn_rcpf(den);
            y[i] = fminf(__builtin_amdgcn_rsqf(V[i]), YMAX);    // V=0 -> inf -> YMAX
            diff[i] = -a0 * (M[i] * r[i]);
            ddot = fmaf(diff[i], w[i], ddot);
        }
    }

    // ---- Steps 1..49 ----
    for (int step = 1; step < NSTEPS; ++step) {
        // wave-reduce ddot -> z
        float dr = ddot;
        #pragma unroll
        for (int off = 32; off >= 1; off >>= 1) dr += __shfl_xor(dr, off, 64);

        const float z  = zb + dr;
        const float e  = __builtin_amdgcn_exp2f(z * NLOG2E);
        const float p  = __builtin_amdgcn_rcpf(1.0f + e);
        const float gz = GZS * (p - tc) * (p * (1.0f - p));

        const float alpha = tbl.alpha[step];
        const float eps2  = tbl.eps2[step];

        ddot = 0.0f;
        const bool exact = (step < 4) || ((step & 3) == 0);

        if (exact) {
            // exact refresh: resync y and r with trans ops
            #pragma unroll
            for (int i = 0; i < EPL; ++i) {
                const float sg = __builtin_amdgcn_fmed3f(diff[i] * SIGN_MUL, -INV_NL1, INV_NL1);
                const float g  = fmaf(gz, w[i], sg);
                M[i] = fmaf(B1f, M[i], g);
                V[i] = fmaf(g, g, V[i] * B2f);

                y[i] = fminf(__builtin_amdgcn_rsqf(V[i]), YMAX);
                const float den = fmaf(V[i], y[i], eps2);       // sqrt(V) + eps
                r[i] = __builtin_amdgcn_rcpf(den);

                diff[i] = fmaf(-alpha, M[i] * r[i], diff[i]);
                ddot = fmaf(diff[i], w[i], ddot);
            }
        } else {
            // cheap: one clamped Newton step each for y (rsqrt) and r (recip)
            #pragma unroll
            for (int i = 0; i < EPL; ++i) {
                const float sg = __builtin_amdgcn_fmed3f(diff[i] * SIGN_MUL, -INV_NL1, INV_NL1);
                const float g  = fmaf(gz, w[i], sg);
                M[i] = fmaf(B1f, M[i], g);
                V[i] = fmaf(g, g, V[i] * B2f);

                // y <- y * clamp(1.5 - 0.5*V*y^2, [0.5, 1.5])
                const float t  = y[i] * y[i];
                const float t2 = V[i] * t;
                float f = fmaf(-0.5f, t2, 1.5f);
                f = __builtin_amdgcn_fmed3f(f, 0.5f, 1.5f);
                y[i] = y[i] * f;

                // den = sqrt(V)+eps (via V*y); r <- r * clamp(2 - den*r, [0.5, 1.5])
                const float den = fmaf(V[i], y[i], eps2);
                const float t5  = den * r[i];
                float f2 = 2.0f - t5;
                f2 = __builtin_amdgcn_fmed3f(f2, 0.5f, 1.5f);
                r[i] = r[i] * f2;

                diff[i] = fmaf(-alpha, M[i] * r[i], diff[i]);
                ddot = fmaf(diff[i], w[i], ddot);
            }
        }
    }

    // Epilogue: reload s0, write sp = s0 + diff
    float4* O4 = reinterpret_cast<float4*>(out + (size_t)row * DDIM);
    #pragma unroll
    for (int c = 0; c < 4; ++c) {
        float4 sv = S4[c * 64 + lane];
        float4 ov;
        ov.x = sv.x + diff[c*4+0];
        ov.y = sv.y + diff[c*4+1];
        ov.z = sv.z + diff[c*4+2];
        ov.w = sv.w + diff[c*4+3];
        O4[c * 64 + lane] = ov;
    }
}

extern "C" void kernel_launch(void* const* d_in, const int* in_sizes, int n_in,
                              void* d_out, int out_size, void* d_ws, size_t ws_size,
                              hipStream_t stream) {
    const float* s     = (const float*)d_in[0];
    const float* tconf = (const float*)d_in[1];
    const float* W     = (const float*)d_in[2];
    const float* bias  = (const float*)d_in[3];
    float* out = (float*)d_out;

    // Host-side per-step Adam constants (double precision, then narrowed).
    StepTbl tbl;
    double b1p = 1.0, b2p = 1.0;
    for (int t = 0; t < NSTEPS; ++t) {
        b1p *= B1_D;
        b2p *= B2_D;
        const double c1 = 1.0 - b1p;                 // 1 - B1^t
        const double c2 = 1.0 - b2p;                 // 1 - B2^t
        const double sc = sqrt(c2 / (1.0 - B2_D));   // sqrt((1-B2^t)/(1-B2))
        tbl.alpha[t] = (float)(LR_D * (1.0 - B1_D) * sc / c1);
        tbl.eps2[t]  = (float)(EPS_D * sc);
    }

    dim3 grid(NROWS / WPB);   // 2048 blocks
    dim3 block(64 * WPB);     // 256 threads
    adam_rows_kernel<<<grid, block, 0, stream>>>(s, tconf, W, bias, out, tbl);
}

// Round 5
// 140.015 us; speedup vs baseline: 11.1637x; 11.1637x over previous
//
#include <hip/hip_runtime.h>
#include <math.h>

// Problem constants (match reference)
#define NROWS   8192
#define DDIM    1024
#define NSTEPS  50
#define EPL     16          // elements per lane: 1024 / 64
#define WPB     4           // waves per block -> 256 threads

// Adam hyperparams (double for host-side table computation)
#define LR_D   0.01
#define B1_D   0.9
#define B2_D   0.999
#define EPS_D  1e-8

struct StepTbl {
    float alpha[NSTEPS];   // LR*(1-B1)*sqrt((1-B2^t)/(1-B2))/(1-B1^t)
    float eps2[NSTEPS];    // EPS*sqrt((1-B2^t)/(1-B2))
    float delta[NSTEPS];   // eps2^2
};

__global__ __launch_bounds__(256) void adam_rows_kernel(
    const float* __restrict__ s,       // [NROWS, DDIM]
    const float* __restrict__ tconf,   // [NROWS, 1]
    const float* __restrict__ W,       // [1, DDIM]
    const float* __restrict__ bias,    // [1]
    float* __restrict__ out,           // [NROWS, DDIM]
    const StepTbl tbl)
{
    const int lane = threadIdx.x & 63;
    const int wave = threadIdx.x >> 6;
    const int row  = blockIdx.x * WPB + wave;

    const float bb = bias[0];
    const float tc = tconf[row];

    const float B1f = 0.9f;
    const float B2f = 0.999f;
    const float GZS = 2.0f / (float)NROWS;
    const float INV_NL1  = 1.1920929e-7f;   // 2^-23 == 1/(NROWS*DDIM) exactly
    const float SIGN_MUL = 3.4e38f;         // lifts any nonzero |diff| above 2^-23
    const float NLOG2E   = -1.44269504f;

    // Loop state: 4 arrays x 16 = 64 floats/lane. No s0 (reloaded at end),
    // no branches in the step loop.
    float w[EPL], diff[EPL], M[EPL], V[EPL];

    const float4* W4 = reinterpret_cast<const float4*>(W);
    const float4* S4 = reinterpret_cast<const float4*>(s + (size_t)row * DDIM);

    // Load w; fold s0 contribution into a single scalar zb = s0.w + b
    float dot0 = 0.0f;
    #pragma unroll
    for (int c = 0; c < 4; ++c) {
        float4 wv = W4[c * 64 + lane];
        float4 sv = S4[c * 64 + lane];
        w[c*4+0] = wv.x; w[c*4+1] = wv.y; w[c*4+2] = wv.z; w[c*4+3] = wv.w;
        dot0 = fmaf(sv.x, wv.x, dot0);
        dot0 = fmaf(sv.y, wv.y, dot0);
        dot0 = fmaf(sv.z, wv.z, dot0);
        dot0 = fmaf(sv.w, wv.w, dot0);
    }
    #pragma unroll
    for (int off = 32; off >= 1; off >>= 1) dot0 += __shfl_xor(dot0, off, 64);
    const float zb = dot0 + bb;

    #pragma unroll
    for (int i = 0; i < EPL; ++i) { diff[i] = 0.0f; M[i] = 0.0f; V[i] = 0.0f; }

    float ddot = 0.0f;   // per-lane partial of diff . w

    for (int step = 0; step < NSTEPS; ++step) {
        // wave-reduce ddot -> z  (step 0: diff==0 -> z = zb)
        float dr = ddot;
        #pragma unroll
        for (int off = 32; off >= 1; off >>= 1) dr += __shfl_xor(dr, off, 64);

        const float z  = zb + dr;
        const float e  = __builtin_amdgcn_exp2f(z * NLOG2E);       // e^-z
        const float p  = __builtin_amdgcn_rcpf(1.0f + e);
        const float gz = GZS * (p - tc) * (p * (1.0f - p));

        const float alpha = tbl.alpha[step];
        const float eps2  = tbl.eps2[step];
        const float delta = tbl.delta[step];

        ddot = 0.0f;
        #pragma unroll
        for (int i = 0; i < EPL; ++i) {
            // sign(diff) * 2^-23, sign(0)=0 exactly
            const float sg = __builtin_amdgcn_fmed3f(diff[i] * SIGN_MUL, -INV_NL1, INV_NL1);
            const float g  = fmaf(gz, w[i], sg);

            M[i] = fmaf(B1f, M[i], g);              // M = b1*M + g
            V[i] = fmaf(g, g, V[i] * B2f);          // V = b2*V + g^2

            // r ~= 1/(sqrt(V)+eps2): one trans op + one Newton polish.
            // u = rsq(V+eps2^2) (exact at V=0); den = V*u + eps2 ~= sqrt(V)+eps2
            const float u   = __builtin_amdgcn_rsqf(V[i] + delta);
            const float den = fmaf(V[i], u, eps2);
            const float e2  = fmaf(-den, u, 2.0f);
            const float r   = u * e2;

            diff[i] = fmaf(-alpha, M[i] * r, diff[i]);
            ddot = fmaf(diff[i], w[i], ddot);
        }
    }

    // Epilogue: reload s0, write sp = s0 + diff
    float4* O4 = reinterpret_cast<float4*>(out + (size_t)row * DDIM);
    #pragma unroll
    for (int c = 0; c < 4; ++c) {
        float4 sv = S4[c * 64 + lane];
        float4 ov;
        ov.x = sv.x + diff[c*4+0];
        ov.y = sv.y + diff[c*4+1];
        ov.z = sv.z + diff[c*4+2];
        ov.w = sv.w + diff[c*4+3];
        O4[c * 64 + lane] = ov;
    }
}

extern "C" void kernel_launch(void* const* d_in, const int* in_sizes, int n_in,
                              void* d_out, int out_size, void* d_ws, size_t ws_size,
                              hipStream_t stream) {
    const float* s     = (const float*)d_in[0];
    const float* tconf = (const float*)d_in[1];
    const float* W     = (const float*)d_in[2];
    const float* bias  = (const float*)d_in[3];
    float* out = (float*)d_out;

    // Host-side per-step Adam constants (double precision, then narrowed).
    StepTbl tbl;
    double b1p = 1.0, b2p = 1.0;
    for (int t = 0; t < NSTEPS; ++t) {
        b1p *= B1_D;
        b2p *= B2_D;
        const double c1 = 1.0 - b1p;                 // 1 - B1^t
        const double c2 = 1.0 - b2p;                 // 1 - B2^t
        const double sc = sqrt(c2 / (1.0 - B2_D));   // sqrt((1-B2^t)/(1-B2))
        tbl.alpha[t] = (float)(LR_D * (1.0 - B1_D) * sc / c1);
        tbl.eps2[t]  = (float)(EPS_D * sc);
        tbl.delta[t] = tbl.eps2[t] * tbl.eps2[t];
    }

    dim3 grid(NROWS / WPB);   // 2048 blocks
    dim3 block(64 * WPB);     // 256 threads
    adam_rows_kernel<<<grid, block, 0, stream>>>(s, tconf, W, bias, out, tbl);
}

// Round 7
// 132.755 us; speedup vs baseline: 11.7742x; 1.0547x over previous
//
#include <hip/hip_runtime.h>
#include <math.h>

// Problem constants (match reference)
#define NROWS   8192
#define DDIM    1024
#define NSTEPS  50
#define NPAIR   8           // float2 pairs per lane (16 elements)
#define WPB     4           // waves per block -> 256 threads

// Adam hyperparams (double for host-side table computation)
#define LR_D   0.01
#define B1_D   0.9
#define B2_D   0.999
#define EPS_D  1e-8

typedef __attribute__((ext_vector_type(2))) float f32x2;

struct StepTbl {
    float alpha[NSTEPS];   // LR*(1-B1)*sqrt((1-B2^t)/(1-B2))/(1-B1^t)
    float eps2[NSTEPS];    // EPS*sqrt((1-B2^t)/(1-B2))
    float delta[NSTEPS];   // eps2^2
};

__global__ __launch_bounds__(256) void adam_rows_kernel(
    const float* __restrict__ s,       // [NROWS, DDIM]
    const float* __restrict__ tconf,   // [NROWS, 1]
    const float* __restrict__ W,       // [1, DDIM]
    const float* __restrict__ bias,    // [1]
    float* __restrict__ out,           // [NROWS, DDIM]
    const StepTbl tbl)
{
    const int lane = threadIdx.x & 63;
    const int wave = threadIdx.x >> 6;
    const int row  = blockIdx.x * WPB + wave;

    const float bb = bias[0];
    const float tc = tconf[row];

    const float GZS      = 2.0f / (float)NROWS;
    const float INV_NL1  = 1.1920929e-7f;   // 2^-23 == 1/(NROWS*DDIM) exactly
    const float SIGN_MUL = 3.4e38f;
    const float NLOG2E   = -1.44269504f;

    const f32x2 b12  = {0.9f, 0.9f};
    const f32x2 b22  = {0.999f, 0.999f};
    const f32x2 sm2  = {SIGN_MUL, SIGN_MUL};
    const f32x2 two2 = {2.0f, 2.0f};

    // Loop state: 4 arrays x 8 pairs = 64 VGPRs
    f32x2 w2[NPAIR], diff2[NPAIR], M2[NPAIR], V2[NPAIR];

    const float4* W4 = reinterpret_cast<const float4*>(W);
    const float4* S4 = reinterpret_cast<const float4*>(s + (size_t)row * DDIM);

    // Load w; fold s0 contribution into a single scalar zb = s0.w + b
    // (serial fma chain, same order as round 5)
    float dot0 = 0.0f;
    #pragma unroll
    for (int c = 0; c < 4; ++c) {
        float4 wv = W4[c * 64 + lane];
        float4 sv = S4[c * 64 + lane];
        w2[2*c+0] = (f32x2){wv.x, wv.y};
        w2[2*c+1] = (f32x2){wv.z, wv.w};
        dot0 = fmaf(sv.x, wv.x, dot0);
        dot0 = fmaf(sv.y, wv.y, dot0);
        dot0 = fmaf(sv.z, wv.z, dot0);
        dot0 = fmaf(sv.w, wv.w, dot0);
    }
    #pragma unroll
    for (int off = 32; off >= 1; off >>= 1) dot0 += __shfl_xor(dot0, off, 64);
    const float zb = dot0 + bb;

    #pragma unroll
    for (int i = 0; i < NPAIR; ++i) {
        diff2[i] = (f32x2){0.0f, 0.0f};
        M2[i]    = (f32x2){0.0f, 0.0f};
        V2[i]    = (f32x2){0.0f, 0.0f};
    }

    float ddot = 0.0f;   // per-lane partial of diff . w

    for (int step = 0; step < NSTEPS; ++step) {
        // wave-reduce ddot -> z  (step 0: diff==0 -> z = zb)
        float dr = ddot;
        #pragma unroll
        for (int off = 32; off >= 1; off >>= 1) dr += __shfl_xor(dr, off, 64);

        const float z  = zb + dr;
        const float e  = __builtin_amdgcn_exp2f(z * NLOG2E);       // e^-z
        const float p  = __builtin_amdgcn_rcpf(1.0f + e);
        const float gz = GZS * (p - tc) * (p * (1.0f - p));

        const float alpha = tbl.alpha[step];
        const float eps2  = tbl.eps2[step];
        const float delta = tbl.delta[step];

        const f32x2 gz2  = {gz, gz};
        const f32x2 nal2 = {-alpha, -alpha};
        const f32x2 ep2  = {eps2, eps2};
        const f32x2 de2  = {delta, delta};

        ddot = 0.0f;
        #pragma unroll
        for (int i = 0; i < NPAIR; ++i) {
            // sign(diff) * 2^-23, sign(0)=0 exactly (per-half med3)
            const f32x2 tm = diff2[i] * sm2;
            f32x2 sg;
            sg.x = __builtin_amdgcn_fmed3f(tm.x, -INV_NL1, INV_NL1);
            sg.y = __builtin_amdgcn_fmed3f(tm.y, -INV_NL1, INV_NL1);

            const f32x2 g = __builtin_elementwise_fma(gz2, w2[i], sg);

            M2[i] = __builtin_elementwise_fma(b12, M2[i], g);        // M = b1*M + g
            V2[i] = __builtin_elementwise_fma(g, g, V2[i] * b22);    // V = b2*V + g^2

            // r = 1/(sqrt(V)+eps2): rsq seed + one Newton polish
            const f32x2 vd = V2[i] + de2;
            f32x2 u;
            u.x = __builtin_amdgcn_rsqf(vd.x);
            u.y = __builtin_amdgcn_rsqf(vd.y);

            const f32x2 den = __builtin_elementwise_fma(V2[i], u, ep2); // ~= sqrt(V)+eps2
            const f32x2 e2  = __builtin_elementwise_fma(-den, u, two2); // 2 - den*u
            const f32x2 r   = u * e2;
            const f32x2 q   = M2[i] * r;

            diff2[i] = __builtin_elementwise_fma(nal2, q, diff2[i]); // diff -= alpha*M*r

            // serial scalar accumulation, same element order as round 5
            ddot = fmaf(diff2[i].x, w2[i].x, ddot);
            ddot = fmaf(diff2[i].y, w2[i].y, ddot);
        }
    }

    // Epilogue: reload s0, write sp = s0 + diff
    float4* O4 = reinterpret_cast<float4*>(out + (size_t)row * DDIM);
    #pragma unroll
    for (int c = 0; c < 4; ++c) {
        float4 sv = S4[c * 64 + lane];
        float4 ov;
        ov.x = sv.x + diff2[2*c+0].x;
        ov.y = sv.y + diff2[2*c+0].y;
        ov.z = sv.z + diff2[2*c+1].x;
        ov.w = sv.w + diff2[2*c+1].y;
        O4[c * 64 + lane] = ov;
    }
}

extern "C" void kernel_launch(void* const* d_in, const int* in_sizes, int n_in,
                              void* d_out, int out_size, void* d_ws, size_t ws_size,
                              hipStream_t stream) {
    const float* s     = (const float*)d_in[0];
    const float* tconf = (const float*)d_in[1];
    const float* W     = (const float*)d_in[2];
    const float* bias  = (const float*)d_in[3];
    float* out = (float*)d_out;

    // Host-side per-step Adam constants (double precision, then narrowed).
    StepTbl tbl;
    double b1p = 1.0, b2p = 1.0;
    for (int t = 0; t < NSTEPS; ++t) {
        b1p *= B1_D;
        b2p *= B2_D;
        const double c1 = 1.0 - b1p;                 // 1 - B1^t
        const double c2 = 1.0 - b2p;                 // 1 - B2^t
        const double sc = sqrt(c2 / (1.0 - B2_D));   // sqrt((1-B2^t)/(1-B2))
        tbl.alpha[t] = (float)(LR_D * (1.0 - B1_D) * sc / c1);
        tbl.eps2[t]  = (float)(EPS_D * sc);
        tbl.delta[t] = tbl.eps2[t] * tbl.eps2[t];
    }

    dim3 grid(NROWS / WPB);   // 2048 blocks
    dim3 block(64 * WPB);     // 256 threads
    adam_rows_kernel<<<grid, block, 0, stream>>>(s, tconf, W, bias, out, tbl);
}

// Round 8
// 123.682 us; speedup vs baseline: 12.6379x; 1.0734x over previous
//
#include <hip/hip_runtime.h>
#include <math.h>

// Problem constants (match reference)
#define NROWS   8192
#define DDIM    1024
#define NSTEPS  50
#define NPAIR   8           // float2 pairs per lane (16 elements)
#define WPB     4           // waves per block -> 256 threads

// Adam hyperparams (double for host-side table computation)
#define LR_D   0.01
#define B1_D   0.9
#define B2_D   0.999
#define EPS_D  1e-8

typedef __attribute__((ext_vector_type(2))) float f32x2;

struct StepTbl {
    float alpha[NSTEPS];   // LR*(1-B1)*sqrt((1-B2^t)/(1-B2))/(1-B1^t)
    float eps2[NSTEPS];    // EPS*sqrt((1-B2^t)/(1-B2))
    float delta[NSTEPS];   // eps2^2
};

// DPP-permuted copy of v (f32 through int bit_cast). bound_ctrl=1 (0 on invalid).
template <int CTRL>
__device__ __forceinline__ float dppf(float v) {
    return __builtin_bit_cast(float,
        __builtin_amdgcn_update_dpp(0, __builtin_bit_cast(int, v), CTRL, 0xF, 0xF, true));
}

// 64-lane all-lanes sum: 4 DPP levels (VALU) + xor16/xor32 (LDS).
__device__ __forceinline__ float wave_sum(float v) {
    v += dppf<0xB1>(v);    // quad_perm {1,0,3,2}  : xor1
    v += dppf<0x4E>(v);    // quad_perm {2,3,0,1}  : xor2
    v += dppf<0x124>(v);   // row_ror:4
    v += dppf<0x128>(v);   // row_ror:8  -> every lane holds its 16-lane row sum
    v += __shfl_xor(v, 16, 64);
    v += __shfl_xor(v, 32, 64);
    return v;
}

// sg = sign(d) * 2^-23 (never 0; caller guarantees d!=+-0 matters not)
__device__ __forceinline__ float sign_bfi(float d, unsigned smask, float smag) {
    float r;
    asm("v_bfi_b32 %0, %1, %2, %3" : "=v"(r) : "v"(smask), "v"(d), "v"(smag));
    return r;
}

__global__ __launch_bounds__(256) void adam_rows_kernel(
    const float* __restrict__ s,       // [NROWS, DDIM]
    const float* __restrict__ tconf,   // [NROWS, 1]
    const float* __restrict__ W,       // [1, DDIM]
    const float* __restrict__ bias,    // [1]
    float* __restrict__ out,           // [NROWS, DDIM]
    const StepTbl tbl)
{
    const int lane = threadIdx.x & 63;
    const int wave = threadIdx.x >> 6;
    const int row  = blockIdx.x * WPB + wave;

    const float bb = bias[0];
    const float tc = tconf[row];

    const float GZS      = 2.0f / (float)NROWS;
    const float NLOG2E   = -1.44269504f;
    const unsigned SMASK = 0x80000000u;
    const float    SMAG  = 1.1920929e-7f;   // 2^-23 == 1/(NROWS*DDIM) exactly

    const f32x2 b12  = {0.9f, 0.9f};
    const f32x2 b22  = {0.999f, 0.999f};
    const f32x2 two2 = {2.0f, 2.0f};

    // Loop state: 4 arrays x 8 pairs = 64 VGPRs
    f32x2 w2[NPAIR], diff2[NPAIR], M2[NPAIR], V2[NPAIR];

    const float4* W4 = reinterpret_cast<const float4*>(W);
    const float4* S4 = reinterpret_cast<const float4*>(s + (size_t)row * DDIM);

    // Load w; fold s0 contribution into a single scalar zb = s0.w + b
    float dot0 = 0.0f;
    #pragma unroll
    for (int c = 0; c < 4; ++c) {
        float4 wv = W4[c * 64 + lane];
        float4 sv = S4[c * 64 + lane];
        w2[2*c+0] = (f32x2){wv.x, wv.y};
        w2[2*c+1] = (f32x2){wv.z, wv.w};
        dot0 = fmaf(sv.x, wv.x, dot0);
        dot0 = fmaf(sv.y, wv.y, dot0);
        dot0 = fmaf(sv.z, wv.z, dot0);
        dot0 = fmaf(sv.w, wv.w, dot0);
    }
    const float zb = wave_sum(dot0) + bb;

    float ddot = 0.0f;   // per-lane partial of diff . w

    // ---- Step 0 peeled: diff == 0 -> sign term exactly 0, M=g, V=g^2 ----
    {
        const float e  = __builtin_amdgcn_exp2f(zb * NLOG2E);
        const float p  = __builtin_amdgcn_rcpf(1.0f + e);
        const float gz = GZS * (p - tc) * (p * (1.0f - p));

        const f32x2 gz2  = {gz, gz};
        const f32x2 nal2 = {-tbl.alpha[0], -tbl.alpha[0]};
        const f32x2 ep2  = {tbl.eps2[0], tbl.eps2[0]};
        const f32x2 de2  = {tbl.delta[0], tbl.delta[0]};

        #pragma unroll
        for (int i = 0; i < NPAIR; ++i) {
            const f32x2 g = gz2 * w2[i];
            M2[i] = g;
            V2[i] = g * g;

            const f32x2 vd = V2[i] + de2;
            f32x2 u;
            u.x = __builtin_amdgcn_rsqf(vd.x);
            u.y = __builtin_amdgcn_rsqf(vd.y);

            const f32x2 den = __builtin_elementwise_fma(V2[i], u, ep2);
            const f32x2 e2  = __builtin_elementwise_fma(-den, u, two2);
            const f32x2 r   = u * e2;
            const f32x2 q   = M2[i] * r;

            diff2[i] = nal2 * q;

            ddot = fmaf(diff2[i].x, w2[i].x, ddot);
            ddot = fmaf(diff2[i].y, w2[i].y, ddot);
        }
    }

    // ---- Steps 1..49 ----
    for (int step = 1; step < NSTEPS; ++step) {
        const float z  = zb + wave_sum(ddot);
        const float e  = __builtin_amdgcn_exp2f(z * NLOG2E);       // e^-z
        const float p  = __builtin_amdgcn_rcpf(1.0f + e);
        const float gz = GZS * (p - tc) * (p * (1.0f - p));

        const float alpha = tbl.alpha[step];
        const float eps2  = tbl.eps2[step];
        const float delta = tbl.delta[step];

        const f32x2 gz2  = {gz, gz};
        const f32x2 nal2 = {-alpha, -alpha};
        const f32x2 ep2  = {eps2, eps2};
        const f32x2 de2  = {delta, delta};

        ddot = 0.0f;
        #pragma unroll
        for (int i = 0; i < NPAIR; ++i) {
            // sg = sign(diff)*2^-23 via v_bfi (diff==+-0 measure-zero for steps>=1)
            f32x2 sg;
            sg.x = sign_bfi(diff2[i].x, SMASK, SMAG);
            sg.y = sign_bfi(diff2[i].y, SMASK, SMAG);

            const f32x2 g = __builtin_elementwise_fma(gz2, w2[i], sg);

            M2[i] = __builtin_elementwise_fma(b12, M2[i], g);        // M = b1*M + g
            V2[i] = __builtin_elementwise_fma(g, g, V2[i] * b22);    // V = b2*V + g^2

            // r = 1/(sqrt(V)+eps2): rsq seed + one Newton polish
            const f32x2 vd = V2[i] + de2;
            f32x2 u;
            u.x = __builtin_amdgcn_rsqf(vd.x);
            u.y = __builtin_amdgcn_rsqf(vd.y);

            const f32x2 den = __builtin_elementwise_fma(V2[i], u, ep2); // ~= sqrt(V)+eps2
            const f32x2 e2  = __builtin_elementwise_fma(-den, u, two2); // 2 - den*u
            const f32x2 r   = u * e2;
            const f32x2 q   = M2[i] * r;

            diff2[i] = __builtin_elementwise_fma(nal2, q, diff2[i]); // diff -= alpha*M*r

            // serial scalar accumulation (round-7 order)
            ddot = fmaf(diff2[i].x, w2[i].x, ddot);
            ddot = fmaf(diff2[i].y, w2[i].y, ddot);
        }
    }

    // Epilogue: reload s0, write sp = s0 + diff
    float4* O4 = reinterpret_cast<float4*>(out + (size_t)row * DDIM);
    #pragma unroll
    for (int c = 0; c < 4; ++c) {
        float4 sv = S4[c * 64 + lane];
        float4 ov;
        ov.x = sv.x + diff2[2*c+0].x;
        ov.y = sv.y + diff2[2*c+0].y;
        ov.z = sv.z + diff2[2*c+1].x;
        ov.w = sv.w + diff2[2*c+1].y;
        O4[c * 64 + lane] = ov;
    }
}

extern "C" void kernel_launch(void* const* d_in, const int* in_sizes, int n_in,
                              void* d_out, int out_size, void* d_ws, size_t ws_size,
                              hipStream_t stream) {
    const float* s     = (const float*)d_in[0];
    const float* tconf = (const float*)d_in[1];
    const float* W     = (const float*)d_in[2];
    const float* bias  = (const float*)d_in[3];
    float* out = (float*)d_out;

    // Host-side per-step Adam constants (double precision, then narrowed).
    StepTbl tbl;
    double b1p = 1.0, b2p = 1.0;
    for (int t = 0; t < NSTEPS; ++t) {
        b1p *= B1_D;
        b2p *= B2_D;
        const double c1 = 1.0 - b1p;                 // 1 - B1^t
        const double c2 = 1.0 - b2p;                 // 1 - B2^t
        const double sc = sqrt(c2 / (1.0 - B2_D));   // sqrt((1-B2^t)/(1-B2))
        tbl.alpha[t] = (float)(LR_D * (1.0 - B1_D) * sc / c1);
        tbl.eps2[t]  = (float)(EPS_D * sc);
        tbl.delta[t] = tbl.eps2[t] * tbl.eps2[t];
    }

    dim3 grid(NROWS / WPB);   // 2048 blocks
    dim3 block(64 * WPB);     // 256 threads
    adam_rows_kernel<<<grid, block, 0, stream>>>(s, tconf, W, bias, out, tbl);
}